// Round 12
// baseline (1399.055 us; speedup 1.0000x reference)
//
#include <hip/hip_runtime.h>
#include <stdint.h>

#define DIM_    1024
#define INTER_  512

typedef short bf16x4 __attribute__((ext_vector_type(4)));
typedef short bf16x8 __attribute__((ext_vector_type(8)));
typedef float f32x4  __attribute__((ext_vector_type(4)));

__device__ __forceinline__ unsigned short f2bf(float f) {
  union { float f; unsigned u; } v; v.f = f;
  return (unsigned short)((v.u + 0x7FFFu + ((v.u >> 16) & 1u)) >> 16);
}
__device__ __forceinline__ unsigned f2bf2(float a, float b) {
  union { float f; unsigned u; } va, vb; va.f = a; vb.f = b;
  unsigned ra = (va.u + 0x7FFFu + ((va.u >> 16) & 1u)) >> 16;
  unsigned rb = (vb.u + 0x7FFFu + ((vb.u >> 16) & 1u)) >> 16;
  return ra | (rb << 16);
}
__device__ __forceinline__ float bfhi(unsigned u) {
  union { unsigned u; float f; } v; v.u = u & 0xffff0000u; return v.f;
}
__device__ __forceinline__ float bflo(unsigned u) {
  union { unsigned u; float f; } v; v.u = u << 16; return v.f;
}

__device__ __forceinline__ void gl16(const void* g, void* l) {
  __builtin_amdgcn_global_load_lds(
      (const __attribute__((address_space(1))) unsigned int*)g,
      (__attribute__((address_space(3))) unsigned int*)l, 16, 0, 0);
}

#define BARX() do { asm volatile("" ::: "memory"); \
                    __builtin_amdgcn_s_barrier();  \
                    asm volatile("" ::: "memory"); } while (0)

// ---------------------------------------------------------------- gate ----
__global__ __launch_bounds__(256) void gate_kernel(
    const float* __restrict__ x, const float* __restrict__ gw,
    const float* __restrict__ gb, int* __restrict__ idx, float* __restrict__ wts,
    unsigned short* __restrict__ xb) {
  __shared__ double s_sc[4][32];
  __shared__ double s_gs[4][8];
  const int wid = threadIdx.x >> 6, lane = threadIdx.x & 63;
  const int t = blockIdx.x * 4 + wid;
  {
    const float* xrow = x + (size_t)t * DIM_ + lane * 16;
    unsigned short* xbrow = xb + (size_t)t * DIM_ + lane * 16;
    float4 f0 = *(const float4*)(xrow);
    float4 f1 = *(const float4*)(xrow + 4);
    float4 f2v = *(const float4*)(xrow + 8);
    float4 f3v = *(const float4*)(xrow + 12);
    uint4 o0, o1;
    o0.x = f2bf2(f0.x, f0.y);  o0.y = f2bf2(f0.z, f0.w);
    o0.z = f2bf2(f1.x, f1.y);  o0.w = f2bf2(f1.z, f1.w);
    o1.x = f2bf2(f2v.x, f2v.y); o1.y = f2bf2(f2v.z, f2v.w);
    o1.z = f2bf2(f3v.x, f3v.y); o1.w = f2bf2(f3v.z, f3v.w);
    *(uint4*)(xbrow) = o0;
    *(uint4*)(xbrow + 8) = o1;
  }
  const int e = lane & 31, half = lane >> 5;
  const float* xr  = x  + (size_t)t * DIM_ + half * 512;
  const float* gwp = gw + (size_t)half * 512 * 32 + e;
  double a0 = 0, a1 = 0, a2 = 0, a3 = 0;
  for (int k = 0; k < 512; k += 4) {
    float4 xv = *(const float4*)(xr + k);
    a0 += (double)xv.x * (double)gwp[(k + 0) * 32];
    a1 += (double)xv.y * (double)gwp[(k + 1) * 32];
    a2 += (double)xv.z * (double)gwp[(k + 2) * 32];
    a3 += (double)xv.w * (double)gwp[(k + 3) * 32];
  }
  double lg = (a0 + a1) + (a2 + a3);
  lg += __shfl_xor(lg, 32);
  lg += (double)gb[e];
  double m = lg;
  #pragma unroll
  for (int d = 1; d < 32; d <<= 1) m = fmax(m, __shfl_xor(m, d));
  double ex = exp(lg - m);
  double ssum = ex;
  #pragma unroll
  for (int d = 1; d < 32; d <<= 1) ssum += __shfl_xor(ssum, d);
  double sc = ex / ssum;
  double p  = __shfl_xor(sc, 1);
  double m1 = fmax(sc, p), n1 = fmin(sc, p);
  double m2 = __shfl_xor(m1, 2), n2 = __shfl_xor(n1, 2);
  double gs = (m1 >= m2) ? (m1 + fmax(n1, m2)) : (m2 + fmax(n2, m1));
  if (lane < 32) {
    s_sc[wid][e] = sc;
    if ((e & 3) == 0) s_gs[wid][e >> 2] = gs;
  }
  __syncthreads();
  if (lane == 0) {
    unsigned kmask = 0;
    for (int it = 0; it < 4; ++it) {
      int bg = 0; double bv = -1.0;
      for (int g = 0; g < 8; ++g)
        if (!((kmask >> g) & 1u) && s_gs[wid][g] > bv) { bv = s_gs[wid][g]; bg = g; }
      kmask |= 1u << bg;
    }
    unsigned umask = 0;
    for (int slot = 0; slot < 4; ++slot) {
      int be = 0; double bv = -1.0;
      for (int ee = 0; ee < 32; ++ee)
        if (((kmask >> (ee >> 2)) & 1u) && !((umask >> ee) & 1u) && s_sc[wid][ee] > bv) {
          bv = s_sc[wid][ee]; be = ee;
        }
      umask |= 1u << be;
      idx[t * 4 + slot] = be;
      wts[t * 4 + slot] = (float)bv;
    }
  }
}

// ------------------------------------------------- dispatch bookkeeping ----
__global__ __launch_bounds__(256) void count_kernel(const int* __restrict__ idx,
                                                    int* __restrict__ meta) {
  __shared__ int h[32];
  int tid = threadIdx.x;
  if (tid < 32) h[tid] = 0;
  __syncthreads();
  atomicAdd(&h[idx[blockIdx.x * 256 + tid]], 1);
  __syncthreads();
  if (tid < 32 && h[tid]) atomicAdd(&meta[tid], h[tid]);
}

__global__ void scan_kernel(int* __restrict__ meta) {
  int lane = threadIdx.x & 63;
  if (lane < 32) {
    int c = meta[lane];
    int pre = c;
    #pragma unroll
    for (int d = 1; d < 32; d <<= 1) { int t = __shfl_up(pre, d); if (lane >= d) pre += t; }
    int excl = pre - c;
    meta[64 + lane] = excl;
    meta[32 + lane] = excl;
    int nt = (c + 255) >> 8;
    int ntp = nt;
    #pragma unroll
    for (int d = 1; d < 32; d <<= 1) { int t = __shfl_up(ntp, d); if (lane >= d) ntp += t; }
    int ntExcl = ntp - nt;
    for (int k = 0; k < nt; ++k) { meta[128 + ntExcl + k] = lane; meta[1184 + ntExcl + k] = k << 8; }
    if (lane == 31) { meta[96] = excl + c; meta[97] = ntExcl + nt; }
  }
}

__global__ __launch_bounds__(256) void scatter_kernel(
    const int* __restrict__ idx, int* __restrict__ meta,
    int* __restrict__ tok, int* __restrict__ inv) {
  int i = blockIdx.x * 256 + threadIdx.x;
  int lane = threadIdx.x & 63;
  int e = idx[i];
  unsigned long long m = ~0ull;
  #pragma unroll
  for (int b = 0; b < 5; ++b) {
    unsigned long long vote = __ballot((e >> b) & 1);
    m &= ((e >> b) & 1) ? vote : ~vote;
  }
  int leader = __ffsll((long long)m) - 1;
  int rank = __popcll(m & ((1ull << lane) - 1));
  int base = 0;
  if (lane == leader) base = atomicAdd(&meta[32 + e], (int)__popcll(m));
  base = __shfl(base, leader);
  int p = base + rank;
  tok[p] = i >> 2;
  inv[i] = p;
}

// ----------------------------------------------------------- repacking ----
// B-image tiles OCTET-MAJOR (conflict-free reads): tile 4KB, k-octet q of
// col j at q*1024 + j*16.
__global__ __launch_bounds__(256) void repack_kernel(
    const float* __restrict__ src, unsigned short* __restrict__ dst,
    int K, int N, int tilesPerMat) {
  const int w = blockIdx.x * 4 + (threadIdx.x >> 6);
  const int j = threadIdx.x & 63;
  const int e = w / tilesPerMat, rem = w % tilesPerMat;
  const int kSteps = K >> 5;
  const int nt = rem / kSteps, kq = rem % kSteps;
  const float* s = src + (size_t)e * K * N + (size_t)(kq * 32) * N + nt * 64 + j;
  float v[32];
  #pragma unroll
  for (int kk = 0; kk < 32; ++kk) v[kk] = s[(size_t)kk * N];
  char* d = (char*)dst + (size_t)w * 4096 + j * 16;
  #pragma unroll
  for (int q = 0; q < 4; ++q) {
    int o = q * 8;
    uint4 tv;
    tv.x = f2bf2(v[o + 0], v[o + 1]);
    tv.y = f2bf2(v[o + 2], v[o + 3]);
    tv.z = f2bf2(v[o + 4], v[o + 5]);
    tv.w = f2bf2(v[o + 6], v[o + 7]);
    *(uint4*)(d + q * 1024) = tv;
  }
}

__global__ __launch_bounds__(256) void repack13_kernel(
    const float* __restrict__ src1, const float* __restrict__ src3,
    unsigned short* __restrict__ dst, int K, int N, int jtTiles) {
  const int w = blockIdx.x * 4 + (threadIdx.x >> 6);
  const int j = threadIdx.x & 63;
  const int kSteps = K >> 5;
  const int tpm = jtTiles * kSteps;
  const int e = w / tpm, rem = w % tpm;
  const int jt = rem / kSteps, kq = rem % kSteps;
  const int jg = jt * 64 + j;
  const int c = ((jg >> 5) << 4) + (jg & 15);
  const float* s = (((jg >> 4) & 1) ? src3 : src1)
                 + (size_t)e * K * N + (size_t)(kq * 32) * N + c;
  float v[32];
  #pragma unroll
  for (int kk = 0; kk < 32; ++kk) v[kk] = s[(size_t)kk * N];
  char* d = (char*)dst + (size_t)w * 4096 + j * 16;
  #pragma unroll
  for (int q = 0; q < 4; ++q) {
    int o = q * 8;
    uint4 tv;
    tv.x = f2bf2(v[o + 0], v[o + 1]);
    tv.y = f2bf2(v[o + 2], v[o + 3]);
    tv.z = f2bf2(v[o + 4], v[o + 5]);
    tv.w = f2bf2(v[o + 6], v[o + 7]);
    *(uint4*)(d + q * 1024) = tv;
  }
}

// ====== 256x128 GEMM core, 3-slot LDS ring (24KB/slot), 2 blocks/CU ========
// ONE barrier per phase: {stage 3 gl16 -> slot (u+2)%3; ds_read frags of
// slot u%3; MFMA; vmcnt(3); barrier}. Hazards: RAW via vmcnt(3)+barrier of
// phase u-1 (slot u staged in phase u-2); WAR via lgkmcnt-before-MFMA +
// end-of-phase barrier; read/stage slots always distinct mod 3.

#define G4_PRE()                                                              \
  const int tid = threadIdx.x, lane = tid & 63, wave = tid >> 6;              \
  const int wm = wave >> 1, wn = wave & 1;                                    \
  const int f = lane & 15, g = lane >> 4;                                     \
  const int rsg = wave * 16 + (lane >> 2);                                    \
  const int qs = (((lane & 3) ^ ((rsg & 3) ^ ((rsg >> 2) & 3))) << 4);        \
  const int wv1k = wave * 1024;                                               \
  const int bso = (wave & 3) * 1024 + lane * 16;                              \
  int aoff[4], boff[4];                                                       \
  _Pragma("unroll")                                                           \
  for (int ii = 0; ii < 4; ++ii) {                                            \
    int u16 = ii * 16 + f;                                                    \
    aoff[ii] = (wm >> 1) * 8192 + (wm & 1) * 4096 + u16 * 64 +                \
               ((g ^ ((u16 & 3) ^ ((u16 >> 2) & 3))) << 4);                   \
    boff[ii] = 16384 + wn * 4096 + g * 1024 + u16 * 16;                       \
  }                                                                           \
  f32x4 acc[4][4];                                                            \
  const f32x4 zz = {0.f, 0.f, 0.f, 0.f};                                      \
  _Pragma("unroll")                                                           \
  for (int mi = 0; mi < 4; ++mi)                                              \
    _Pragma("unroll")                                                         \
    for (int ni = 0; ni < 4; ++ni) acc[mi][ni] = zz;

#define G4_STAGE(td, u_)                                                      \
  gl16(pA0 + (u_) * 64, (td) + wv1k);                                         \
  gl16(pA1 + (u_) * 64, (td) + 8192 + wv1k);                                  \
  gl16(pB + (size_t)(u_) * 4096, (td) + 16384 + wv1k);

#define G4_BODY(NU)                                                           \
  {                                                                           \
    G4_STAGE(lds, 0);                                                         \
    G4_STAGE(lds + 24576, ((NU) > 1 ? 1 : 0));                                \
    asm volatile("s_waitcnt vmcnt(3)" ::: "memory");                          \
    BARX();                                                                   \
  }                                                                           \
  int bc = 0, bt = 49152;                                                     \
  for (int u = 0; u < (NU); ++u) {                                            \
    int u_ = u + 2; if (u_ > (NU) - 1) u_ = (NU) - 1;                         \
    char* td = lds + bt;                                                      \
    G4_STAGE(td, u_);                                                         \
    const char* cb = lds + bc;                                                \
    bf16x8 af[4], bv[4];                                                      \
    _Pragma("unroll")                                                         \
    for (int mi = 0; mi < 4; ++mi) af[mi] = *(const bf16x8*)(cb + aoff[mi]);  \
    _Pragma("unroll")                                                         \
    for (int ni = 0; ni < 4; ++ni) bv[ni] = *(const bf16x8*)(cb + boff[ni]);  \
    __builtin_amdgcn_s_setprio(1);                                            \
    _Pragma("unroll")                                                         \
    for (int ni = 0; ni < 4; ++ni)                                            \
      _Pragma("unroll")                                                       \
      for (int mi = 0; mi < 4; ++mi)                                          \
        acc[mi][ni] = __builtin_amdgcn_mfma_f32_16x16x32_bf16(                \
            af[mi], bv[ni], acc[mi][ni], 0, 0, 0);                            \
    __builtin_amdgcn_s_setprio(0);                                            \
    asm volatile("s_waitcnt vmcnt(3)" ::: "memory");                          \
    BARX();                                                                   \
    bc = (bc == 49152) ? 0 : bc + 24576;                                      \
    bt = (bt == 49152) ? 0 : bt + 24576;                                      \
  }

// XCD-chunked flat swizzle: consecutive work-ids land on the same XCD.
#define XCD_SWZ(GXv)                                                          \
  const int nb_ = gridDim.x;                                                  \
  const int b_ = blockIdx.x;                                                  \
  const int w_ = (b_ & 7) * (nb_ >> 3) + (b_ >> 3);                           \
  const int bx = w_ % (GXv);                                                  \
  const int by = w_ / (GXv);

// --------------------------------------------------------- shared GEMM1 ----
__global__ __launch_bounds__(512, 4) void s1_kernel(
    const unsigned short* __restrict__ xb, const unsigned short* __restrict__ w13,
    const float* __restrict__ sb1, const float* __restrict__ sb3,
    unsigned short* __restrict__ Hs) {
  __shared__ char lds[73728];
  XCD_SWZ(16);
  const int m0 = by * 256;
  G4_PRE();
  const char* pA0 = (const char*)xb + (size_t)(m0 + rsg) * 2048 + qs;
  const char* pA1 = pA0 + (size_t)128 * 2048;
  const char* pB = (const char*)w13 + ((size_t)(bx * 2 + (wave >> 2)) * 32) * 4096 + bso;
  G4_BODY(32);
  const int colb = bx * 64;
  #pragma unroll
  for (int p2 = 0; p2 < 2; ++p2) {
    int c = colb + wn * 32 + p2 * 16 + f;
    float bb1 = sb1[c], bb3 = sb3[c];
    #pragma unroll
    for (int mi = 0; mi < 4; ++mi) {
      int row = m0 + wm * 64 + mi * 16 + g * 4;
      #pragma unroll
      for (int r = 0; r < 4; ++r) {
        float v1 = acc[mi][2 * p2][r] + bb1;
        float v3 = acc[mi][2 * p2 + 1][r] + bb3;
        float h = (v1 / (1.f + __expf(-v1))) * v3;
        Hs[(size_t)(row + r) * 1024 + c] = f2bf(h);
      }
    }
  }
}

// --------------------------------------------------------- shared GEMM2 ----
__global__ __launch_bounds__(512, 4) void s2_kernel(
    const unsigned short* __restrict__ Hs, const unsigned short* __restrict__ b2i,
    const float* __restrict__ sb2, float* __restrict__ out) {
  __shared__ char lds[73728];
  XCD_SWZ(8);
  const int m0 = by * 256;
  G4_PRE();
  const char* pA0 = (const char*)Hs + (size_t)(m0 + rsg) * 2048 + qs;
  const char* pA1 = pA0 + (size_t)128 * 2048;
  const char* pB = (const char*)b2i + ((size_t)(bx * 2 + (wave >> 2)) * 32) * 4096 + bso;
  G4_BODY(32);
  #pragma unroll
  for (int ni = 0; ni < 4; ++ni) {
    int c = bx * 128 + wn * 64 + ni * 16 + f;
    float bb = sb2[c];
    #pragma unroll
    for (int mi = 0; mi < 4; ++mi) {
      int row = m0 + wm * 64 + mi * 16 + g * 4;
      #pragma unroll
      for (int r = 0; r < 4; ++r)
        out[(size_t)(row + r) * 1024 + c] = acc[mi][ni][r] + bb;
    }
  }
}

// --------------------------------------------------------- routed GEMM1 ----
__global__ __launch_bounds__(512, 4) void g1_kernel(
    const unsigned short* __restrict__ xb, const unsigned short* __restrict__ w13,
    const float* __restrict__ b1, const float* __restrict__ b3,
    const int* __restrict__ tok, const int* __restrict__ meta,
    unsigned short* __restrict__ H) {
  __shared__ char lds[73728];
  XCD_SWZ(8);
  if (by >= meta[97]) return;
  const int e = meta[128 + by], m0 = meta[1184 + by];
  const int off_e = meta[64 + e], nrem = meta[e] - m0;
  G4_PRE();
  const int ix0 = off_e + m0 + ((rsg < nrem) ? rsg : 0);
  const int ix1 = off_e + m0 + ((rsg + 128 < nrem) ? rsg + 128 : 0);
  const char* pA0 = (const char*)xb + (size_t)tok[ix0] * 2048 + qs;
  const char* pA1 = (const char*)xb + (size_t)tok[ix1] * 2048 + qs;
  const char* pB = (const char*)w13 + ((size_t)(e * 16 + bx * 2 + (wave >> 2)) * 32) * 4096 + bso;
  G4_BODY(32);
  const int colb = bx * 64;
  #pragma unroll
  for (int p2 = 0; p2 < 2; ++p2) {
    int c = colb + wn * 32 + p2 * 16 + f;
    float bb1 = b1[e * 512 + c], bb3 = b3[e * 512 + c];
    #pragma unroll
    for (int mi = 0; mi < 4; ++mi) {
      int row = wm * 64 + mi * 16 + g * 4;
      #pragma unroll
      for (int r = 0; r < 4; ++r) {
        if (row + r < nrem) {
          float v1 = acc[mi][2 * p2][r] + bb1;
          float v3 = acc[mi][2 * p2 + 1][r] + bb3;
          float h = (v1 / (1.f + __expf(-v1))) * v3;
          H[(size_t)(off_e + m0 + row + r) * 512 + c] = f2bf(h);
        }
      }
    }
  }
}

// --------------------------------------------------------- routed GEMM2 ----
__global__ __launch_bounds__(512, 4) void g2_kernel(
    const unsigned short* __restrict__ H, const unsigned short* __restrict__ w2i,
    const float* __restrict__ b2, const int* __restrict__ meta,
    unsigned short* __restrict__ Y, int cbase) {
  __shared__ char lds[73728];
  XCD_SWZ(4);
  if (by >= meta[97]) return;
  const int e = meta[128 + by], m0 = meta[1184 + by];
  const int off_e = meta[64 + e], nrem = meta[e] - m0;
  G4_PRE();
  const int ix0 = off_e + m0 + ((rsg < nrem) ? rsg : 0);
  const int ix1 = off_e + m0 + ((rsg + 128 < nrem) ? rsg + 128 : 0);
  const char* pA0 = (const char*)H + (size_t)ix0 * 1024 + qs;
  const char* pA1 = (const char*)H + (size_t)ix1 * 1024 + qs;
  const int nt0 = (cbase >> 6) + bx * 2;
  const char* pB = (const char*)w2i + ((size_t)(e * 16 + nt0 + (wave >> 2)) * 16) * 4096 + bso;
  G4_BODY(16);
  #pragma unroll
  for (int ni = 0; ni < 4; ++ni) {
    int ycol = bx * 128 + wn * 64 + ni * 16 + f;
    float bb = b2[e * 1024 + cbase + ycol];
    #pragma unroll
    for (int mi = 0; mi < 4; ++mi) {
      int row = wm * 64 + mi * 16 + g * 4;
      #pragma unroll
      for (int r = 0; r < 4; ++r) {
        if (row + r < nrem)
          Y[(size_t)(off_e + m0 + row + r) * 512 + ycol] = f2bf(acc[mi][ni][r] + bb);
      }
    }
  }
}

// ------------------------------------------------------------- combine ----
__global__ __launch_bounds__(256) void combine_kernel(
    const unsigned short* __restrict__ Y, const int* __restrict__ inv,
    const float* __restrict__ wts, float* __restrict__ out, int cbase) {
  int t = blockIdx.x * 2 + (threadIdx.x >> 7);
  int c = (threadIdx.x & 127) * 4;
  int4 iv = *(const int4*)(inv + t * 4);
  float4 wv = *(const float4*)(wts + t * 4);
  float* op = out + (size_t)t * 1024 + cbase + c;
  float4 o = *(float4*)op;
  uint2 u;
  u = *(const uint2*)(Y + (size_t)iv.x * 512 + c);
  o.x += wv.x * bflo(u.x); o.y += wv.x * bfhi(u.x);
  o.z += wv.x * bflo(u.y); o.w += wv.x * bfhi(u.y);
  u = *(const uint2*)(Y + (size_t)iv.y * 512 + c);
  o.x += wv.y * bflo(u.x); o.y += wv.y * bfhi(u.x);
  o.z += wv.y * bflo(u.y); o.w += wv.y * bfhi(u.y);
  u = *(const uint2*)(Y + (size_t)iv.z * 512 + c);
  o.x += wv.z * bflo(u.x); o.y += wv.z * bfhi(u.x);
  o.z += wv.z * bflo(u.y); o.w += wv.z * bfhi(u.y);
  u = *(const uint2*)(Y + (size_t)iv.w * 512 + c);
  o.x += wv.w * bflo(u.x); o.y += wv.w * bfhi(u.x);
  o.z += wv.w * bflo(u.y); o.w += wv.w * bfhi(u.y);
  *(float4*)op = o;
}

// ------------------------------------------------------------------ host ----
extern "C" void kernel_launch(void* const* d_in, const int* in_sizes, int n_in,
                              void* d_out, int out_size, void* d_ws, size_t ws_size,
                              hipStream_t stream) {
  const float* x   = (const float*)d_in[0];
  const float* gw  = (const float*)d_in[1];
  const float* gb  = (const float*)d_in[2];
  const float* w1  = (const float*)d_in[3];
  const float* b1  = (const float*)d_in[4];
  const float* w3  = (const float*)d_in[5];
  const float* b3  = (const float*)d_in[6];
  const float* w2  = (const float*)d_in[7];
  const float* b2  = (const float*)d_in[8];
  const float* sw1 = (const float*)d_in[9];
  const float* sb1 = (const float*)d_in[10];
  const float* sw3 = (const float*)d_in[11];
  const float* sb3 = (const float*)d_in[12];
  const float* sw2 = (const float*)d_in[13];
  const float* sb2 = (const float*)d_in[14];
  float* out = (float*)d_out;
  char* ws = (char*)d_ws;

  const size_t OFF_XB   = 134217728;
  const size_t OFF_W13I = 201326592;
  const size_t OFF_W2I  = 268435456;
  const size_t OFF_S13I = 301989888;
  const size_t OFF_SW2I = 306184192;
  const size_t OFF_IDX  = 308281344;
  const size_t OFF_WTS  = 308805632;
  const size_t OFF_TOK  = 309329920;
  const size_t OFF_INV  = 309854208;
  const size_t OFF_META = 310378496;
  if (ws_size < OFF_META + 8960) return;

  unsigned short* H    = (unsigned short*)ws;
  unsigned short* xb   = (unsigned short*)(ws + OFF_XB);
  unsigned short* Yb   = (unsigned short*)(ws + OFF_XB);
  unsigned short* w13i = (unsigned short*)(ws + OFF_W13I);
  unsigned short* w2i  = (unsigned short*)(ws + OFF_W2I);
  unsigned short* s13i = (unsigned short*)(ws + OFF_S13I);
  unsigned short* sw2i = (unsigned short*)(ws + OFF_SW2I);
  int*   idx  = (int*)(ws + OFF_IDX);
  float* wts  = (float*)(ws + OFF_WTS);
  int*   tokl = (int*)(ws + OFF_TOK);
  int*   inv  = (int*)(ws + OFF_INV);
  int*   meta = (int*)(ws + OFF_META);

  hipMemsetAsync(meta, 0, 128, stream);
  gate_kernel<<<dim3(8192), dim3(256), 0, stream>>>(x, gw, gb, idx, wts, xb);
  count_kernel<<<dim3(512), dim3(256), 0, stream>>>(idx, meta);
  scan_kernel<<<dim3(1), dim3(64), 0, stream>>>(meta);
  scatter_kernel<<<dim3(512), dim3(256), 0, stream>>>(idx, meta, tokl, inv);
  repack13_kernel<<<dim3(4096), dim3(256), 0, stream>>>(w1, w3, w13i, 1024, 512, 16);
  repack_kernel<<<dim3(2048), dim3(256), 0, stream>>>(w2, w2i, 512, 1024, 256);
  repack13_kernel<<<dim3(256), dim3(256), 0, stream>>>(sw1, sw3, s13i, 1024, 1024, 32);
  repack_kernel<<<dim3(128), dim3(256), 0, stream>>>(sw2, sw2i, 1024, 1024, 512);
  s1_kernel<<<dim3(2048), dim3(512), 0, stream>>>(xb, s13i, sb1, sb3, H);
  s2_kernel<<<dim3(1024), dim3(512), 0, stream>>>(H, sw2i, sb2, out);
  g1_kernel<<<dim3(4352), dim3(512), 0, stream>>>(xb, w13i, b1, b3, tokl, meta, H);
  g2_kernel<<<dim3(2176), dim3(512), 0, stream>>>(H, w2i, b2, meta, Yb, 0);
  combine_kernel<<<dim3(16384), dim3(256), 0, stream>>>(Yb, inv, wts, out, 0);
  g2_kernel<<<dim3(2176), dim3(512), 0, stream>>>(H, w2i, b2, meta, Yb, 512);
  combine_kernel<<<dim3(16384), dim3(256), 0, stream>>>(Yb, inv, wts, out, 512);
}

// Round 13
// 1317.694 us; speedup vs baseline: 1.0617x; 1.0617x over previous
//
#include <hip/hip_runtime.h>
#include <stdint.h>

#define DIM_    1024
#define INTER_  512

typedef short bf16x4 __attribute__((ext_vector_type(4)));
typedef short bf16x8 __attribute__((ext_vector_type(8)));
typedef float f32x4  __attribute__((ext_vector_type(4)));

__device__ __forceinline__ unsigned short f2bf(float f) {
  union { float f; unsigned u; } v; v.f = f;
  return (unsigned short)((v.u + 0x7FFFu + ((v.u >> 16) & 1u)) >> 16);
}
__device__ __forceinline__ unsigned f2bf2(float a, float b) {
  union { float f; unsigned u; } va, vb; va.f = a; vb.f = b;
  unsigned ra = (va.u + 0x7FFFu + ((va.u >> 16) & 1u)) >> 16;
  unsigned rb = (vb.u + 0x7FFFu + ((vb.u >> 16) & 1u)) >> 16;
  return ra | (rb << 16);
}
__device__ __forceinline__ float bfhi(unsigned u) {
  union { unsigned u; float f; } v; v.u = u & 0xffff0000u; return v.f;
}
__device__ __forceinline__ float bflo(unsigned u) {
  union { unsigned u; float f; } v; v.u = u << 16; return v.f;
}

__device__ __forceinline__ void gl16(const void* g, void* l) {
  __builtin_amdgcn_global_load_lds(
      (const __attribute__((address_space(1))) unsigned int*)g,
      (__attribute__((address_space(3))) unsigned int*)l, 16, 0, 0);
}

#define BARX() do { asm volatile("" ::: "memory"); \
                    __builtin_amdgcn_s_barrier();  \
                    asm volatile("" ::: "memory"); } while (0)

// ---------------------------------------------------------------- bodies ----
__device__ __forceinline__ void gate_body(
    int bI, const float* __restrict__ x, const float* __restrict__ gw,
    const float* __restrict__ gb, int* __restrict__ idx, float* __restrict__ wts,
    unsigned short* __restrict__ xb) {
  __shared__ double s_sc[4][32];
  __shared__ double s_gs[4][8];
  const int wid = threadIdx.x >> 6, lane = threadIdx.x & 63;
  const int t = bI * 4 + wid;
  {
    const float* xrow = x + (size_t)t * DIM_ + lane * 16;
    unsigned short* xbrow = xb + (size_t)t * DIM_ + lane * 16;
    float4 f0 = *(const float4*)(xrow);
    float4 f1 = *(const float4*)(xrow + 4);
    float4 f2v = *(const float4*)(xrow + 8);
    float4 f3v = *(const float4*)(xrow + 12);
    uint4 o0, o1;
    o0.x = f2bf2(f0.x, f0.y);  o0.y = f2bf2(f0.z, f0.w);
    o0.z = f2bf2(f1.x, f1.y);  o0.w = f2bf2(f1.z, f1.w);
    o1.x = f2bf2(f2v.x, f2v.y); o1.y = f2bf2(f2v.z, f2v.w);
    o1.z = f2bf2(f3v.x, f3v.y); o1.w = f2bf2(f3v.z, f3v.w);
    *(uint4*)(xbrow) = o0;
    *(uint4*)(xbrow + 8) = o1;
  }
  const int e = lane & 31, half = lane >> 5;
  const float* xr  = x  + (size_t)t * DIM_ + half * 512;
  const float* gwp = gw + (size_t)half * 512 * 32 + e;
  double a0 = 0, a1 = 0, a2 = 0, a3 = 0;
  for (int k = 0; k < 512; k += 4) {
    float4 xv = *(const float4*)(xr + k);
    a0 += (double)xv.x * (double)gwp[(k + 0) * 32];
    a1 += (double)xv.y * (double)gwp[(k + 1) * 32];
    a2 += (double)xv.z * (double)gwp[(k + 2) * 32];
    a3 += (double)xv.w * (double)gwp[(k + 3) * 32];
  }
  double lg = (a0 + a1) + (a2 + a3);
  lg += __shfl_xor(lg, 32);
  lg += (double)gb[e];
  double m = lg;
  #pragma unroll
  for (int d = 1; d < 32; d <<= 1) m = fmax(m, __shfl_xor(m, d));
  double ex = exp(lg - m);
  double ssum = ex;
  #pragma unroll
  for (int d = 1; d < 32; d <<= 1) ssum += __shfl_xor(ssum, d);
  double sc = ex / ssum;
  double p  = __shfl_xor(sc, 1);
  double m1 = fmax(sc, p), n1 = fmin(sc, p);
  double m2 = __shfl_xor(m1, 2), n2 = __shfl_xor(n1, 2);
  double gs = (m1 >= m2) ? (m1 + fmax(n1, m2)) : (m2 + fmax(n2, m1));
  if (lane < 32) {
    s_sc[wid][e] = sc;
    if ((e & 3) == 0) s_gs[wid][e >> 2] = gs;
  }
  __syncthreads();
  if (lane == 0) {
    unsigned kmask = 0;
    for (int it = 0; it < 4; ++it) {
      int bg = 0; double bv = -1.0;
      for (int g = 0; g < 8; ++g)
        if (!((kmask >> g) & 1u) && s_gs[wid][g] > bv) { bv = s_gs[wid][g]; bg = g; }
      kmask |= 1u << bg;
    }
    unsigned umask = 0;
    for (int slot = 0; slot < 4; ++slot) {
      int be = 0; double bv = -1.0;
      for (int ee = 0; ee < 32; ++ee)
        if (((kmask >> (ee >> 2)) & 1u) && !((umask >> ee) & 1u) && s_sc[wid][ee] > bv) {
          bv = s_sc[wid][ee]; be = ee;
        }
      umask |= 1u << be;
      idx[t * 4 + slot] = be;
      wts[t * 4 + slot] = (float)bv;
    }
  }
}

// B-image OCTET-MAJOR (conflict-free frag reads): 4KB tile, k-octet q of
// col j at q*1024 + j*16.
__device__ __forceinline__ void repack_body(
    int bI, const float* __restrict__ src, unsigned short* __restrict__ dst,
    int K, int N, int tilesPerMat) {
  const int w = bI * 4 + (threadIdx.x >> 6);
  const int j = threadIdx.x & 63;
  const int e = w / tilesPerMat, rem = w % tilesPerMat;
  const int kSteps = K >> 5;
  const int nt = rem / kSteps, kq = rem % kSteps;
  const float* s = src + (size_t)e * K * N + (size_t)(kq * 32) * N + nt * 64 + j;
  float v[32];
  #pragma unroll
  for (int kk = 0; kk < 32; ++kk) v[kk] = s[(size_t)kk * N];
  char* d = (char*)dst + (size_t)w * 4096 + j * 16;
  #pragma unroll
  for (int q = 0; q < 4; ++q) {
    int o = q * 8;
    uint4 tv;
    tv.x = f2bf2(v[o + 0], v[o + 1]);
    tv.y = f2bf2(v[o + 2], v[o + 3]);
    tv.z = f2bf2(v[o + 4], v[o + 5]);
    tv.w = f2bf2(v[o + 6], v[o + 7]);
    *(uint4*)(d + q * 1024) = tv;
  }
}

__device__ __forceinline__ void repack13_body(
    int bI, const float* __restrict__ src1, const float* __restrict__ src3,
    unsigned short* __restrict__ dst, int K, int N, int jtTiles) {
  const int w = bI * 4 + (threadIdx.x >> 6);
  const int j = threadIdx.x & 63;
  const int kSteps = K >> 5;
  const int tpm = jtTiles * kSteps;
  const int e = w / tpm, rem = w % tpm;
  const int jt = rem / kSteps, kq = rem % kSteps;
  const int jg = jt * 64 + j;
  const int c = ((jg >> 5) << 4) + (jg & 15);
  const float* s = (((jg >> 4) & 1) ? src3 : src1)
                 + (size_t)e * K * N + (size_t)(kq * 32) * N + c;
  float v[32];
  #pragma unroll
  for (int kk = 0; kk < 32; ++kk) v[kk] = s[(size_t)kk * N];
  char* d = (char*)dst + (size_t)w * 4096 + j * 16;
  #pragma unroll
  for (int q = 0; q < 4; ++q) {
    int o = q * 8;
    uint4 tv;
    tv.x = f2bf2(v[o + 0], v[o + 1]);
    tv.y = f2bf2(v[o + 2], v[o + 3]);
    tv.z = f2bf2(v[o + 4], v[o + 5]);
    tv.w = f2bf2(v[o + 6], v[o + 7]);
    *(uint4*)(d + q * 1024) = tv;
  }
}

// ====== 256x128 GEMM core, 3-slot LDS ring (24KB/slot), 2 blocks/CU ========
#define G4_PRE()                                                              \
  const int tid = threadIdx.x, lane = tid & 63, wave = tid >> 6;              \
  const int wm = wave >> 1, wn = wave & 1;                                    \
  const int f = lane & 15, g = lane >> 4;                                     \
  const int rsg = wave * 16 + (lane >> 2);                                    \
  const int qs = (((lane & 3) ^ ((rsg & 3) ^ ((rsg >> 2) & 3))) << 4);        \
  const int wv1k = wave * 1024;                                               \
  const int bso = (wave & 3) * 1024 + lane * 16;                              \
  int aoff[4], boff[4];                                                       \
  _Pragma("unroll")                                                           \
  for (int ii = 0; ii < 4; ++ii) {                                            \
    int u16 = ii * 16 + f;                                                    \
    aoff[ii] = (wm >> 1) * 8192 + (wm & 1) * 4096 + u16 * 64 +                \
               ((g ^ ((u16 & 3) ^ ((u16 >> 2) & 3))) << 4);                   \
    boff[ii] = 16384 + wn * 4096 + g * 1024 + u16 * 16;                       \
  }                                                                           \
  f32x4 acc[4][4];                                                            \
  const f32x4 zz = {0.f, 0.f, 0.f, 0.f};                                      \
  _Pragma("unroll")                                                           \
  for (int mi = 0; mi < 4; ++mi)                                              \
    _Pragma("unroll")                                                         \
    for (int ni = 0; ni < 4; ++ni) acc[mi][ni] = zz;

#define G4_STAGE(td, u_)                                                      \
  gl16(pA0 + (u_) * 64, (td) + wv1k);                                         \
  gl16(pA1 + (u_) * 64, (td) + 8192 + wv1k);                                  \
  gl16(pB + (size_t)(u_) * 4096, (td) + 16384 + wv1k);

#define G4_BODY(NU)                                                           \
  {                                                                           \
    G4_STAGE(lds, 0);                                                         \
    G4_STAGE(lds + 24576, ((NU) > 1 ? 1 : 0));                                \
    asm volatile("s_waitcnt vmcnt(3)" ::: "memory");                          \
    BARX();                                                                   \
  }                                                                           \
  int bc = 0, bt = 49152;                                                     \
  for (int u = 0; u < (NU); ++u) {                                            \
    int u_ = u + 2; if (u_ > (NU) - 1) u_ = (NU) - 1;                         \
    char* td = lds + bt;                                                      \
    G4_STAGE(td, u_);                                                         \
    const char* cb = lds + bc;                                                \
    bf16x8 af[4], bv[4];                                                      \
    _Pragma("unroll")                                                         \
    for (int mi = 0; mi < 4; ++mi) af[mi] = *(const bf16x8*)(cb + aoff[mi]);  \
    _Pragma("unroll")                                                         \
    for (int ni = 0; ni < 4; ++ni) bv[ni] = *(const bf16x8*)(cb + boff[ni]);  \
    __builtin_amdgcn_s_setprio(1);                                            \
    _Pragma("unroll")                                                         \
    for (int ni = 0; ni < 4; ++ni)                                            \
      _Pragma("unroll")                                                       \
      for (int mi = 0; mi < 4; ++mi)                                          \
        acc[mi][ni] = __builtin_amdgcn_mfma_f32_16x16x32_bf16(                \
            af[mi], bv[ni], acc[mi][ni], 0, 0, 0);                            \
    __builtin_amdgcn_s_setprio(0);                                            \
    asm volatile("s_waitcnt vmcnt(3)" ::: "memory");                          \
    BARX();                                                                   \
    bc = (bc == 49152) ? 0 : bc + 24576;                                      \
    bt = (bt == 49152) ? 0 : bt + 24576;                                      \
  }

__device__ __forceinline__ int2 xcd_swz(int id, int nb, int gx) {
  int w = (id & 7) * (nb >> 3) + (id >> 3);
  int2 r; r.x = w % gx; r.y = w / gx; return r;
}

__device__ __forceinline__ void s1_body(int bx, int by,
    const unsigned short* __restrict__ xb, const unsigned short* __restrict__ w13,
    const float* __restrict__ sb1, const float* __restrict__ sb3,
    unsigned short* __restrict__ Hs, char* lds) {
  const int m0 = by * 256;
  G4_PRE();
  const char* pA0 = (const char*)xb + (size_t)(m0 + rsg) * 2048 + qs;
  const char* pA1 = pA0 + (size_t)128 * 2048;
  const char* pB = (const char*)w13 + ((size_t)(bx * 2 + (wave >> 2)) * 32) * 4096 + bso;
  G4_BODY(32);
  const int colb = bx * 64;
  #pragma unroll
  for (int p2 = 0; p2 < 2; ++p2) {
    int c = colb + wn * 32 + p2 * 16 + f;
    float bb1 = sb1[c], bb3 = sb3[c];
    #pragma unroll
    for (int mi = 0; mi < 4; ++mi) {
      int row = m0 + wm * 64 + mi * 16 + g * 4;
      #pragma unroll
      for (int r = 0; r < 4; ++r) {
        float v1 = acc[mi][2 * p2][r] + bb1;
        float v3 = acc[mi][2 * p2 + 1][r] + bb3;
        float h = (v1 / (1.f + __expf(-v1))) * v3;
        Hs[(size_t)(row + r) * 1024 + c] = f2bf(h);
      }
    }
  }
}

__device__ __forceinline__ void s2_body(int bx, int by,
    const unsigned short* __restrict__ Hs, const unsigned short* __restrict__ b2i,
    const float* __restrict__ sb2, float* __restrict__ out, char* lds) {
  const int m0 = by * 256;
  G4_PRE();
  const char* pA0 = (const char*)Hs + (size_t)(m0 + rsg) * 2048 + qs;
  const char* pA1 = pA0 + (size_t)128 * 2048;
  const char* pB = (const char*)b2i + ((size_t)(bx * 2 + (wave >> 2)) * 32) * 4096 + bso;
  G4_BODY(32);
  #pragma unroll
  for (int ni = 0; ni < 4; ++ni) {
    int c = bx * 128 + wn * 64 + ni * 16 + f;
    float bb = sb2[c];
    #pragma unroll
    for (int mi = 0; mi < 4; ++mi) {
      int row = m0 + wm * 64 + mi * 16 + g * 4;
      #pragma unroll
      for (int r = 0; r < 4; ++r)
        out[(size_t)(row + r) * 1024 + c] = acc[mi][ni][r] + bb;
    }
  }
}

__device__ __forceinline__ void g1_body(int bx, int by,
    const unsigned short* __restrict__ xb, const unsigned short* __restrict__ w13,
    const float* __restrict__ b1, const float* __restrict__ b3,
    const int* __restrict__ tok, const int* __restrict__ meta,
    unsigned short* __restrict__ H, char* lds) {
  if (by >= meta[97]) return;
  const int e = meta[128 + by], m0 = meta[1184 + by];
  const int off_e = meta[64 + e], nrem = meta[e] - m0;
  G4_PRE();
  const int ix0 = off_e + m0 + ((rsg < nrem) ? rsg : 0);
  const int ix1 = off_e + m0 + ((rsg + 128 < nrem) ? rsg + 128 : 0);
  const char* pA0 = (const char*)xb + (size_t)tok[ix0] * 2048 + qs;
  const char* pA1 = (const char*)xb + (size_t)tok[ix1] * 2048 + qs;
  const char* pB = (const char*)w13 + ((size_t)(e * 16 + bx * 2 + (wave >> 2)) * 32) * 4096 + bso;
  G4_BODY(32);
  const int colb = bx * 64;
  #pragma unroll
  for (int p2 = 0; p2 < 2; ++p2) {
    int c = colb + wn * 32 + p2 * 16 + f;
    float bb1 = b1[e * 512 + c], bb3 = b3[e * 512 + c];
    #pragma unroll
    for (int mi = 0; mi < 4; ++mi) {
      int row = wm * 64 + mi * 16 + g * 4;
      #pragma unroll
      for (int r = 0; r < 4; ++r) {
        if (row + r < nrem) {
          float v1 = acc[mi][2 * p2][r] + bb1;
          float v3 = acc[mi][2 * p2 + 1][r] + bb3;
          float h = (v1 / (1.f + __expf(-v1))) * v3;
          H[(size_t)(off_e + m0 + row + r) * 512 + c] = f2bf(h);
        }
      }
    }
  }
}

__device__ __forceinline__ void g2_body(int bx, int by,
    const unsigned short* __restrict__ H, const unsigned short* __restrict__ w2i,
    const float* __restrict__ b2, const int* __restrict__ meta,
    unsigned short* __restrict__ Y, int cbase, char* lds) {
  if (by >= meta[97]) return;
  const int e = meta[128 + by], m0 = meta[1184 + by];
  const int off_e = meta[64 + e], nrem = meta[e] - m0;
  G4_PRE();
  const int ix0 = off_e + m0 + ((rsg < nrem) ? rsg : 0);
  const int ix1 = off_e + m0 + ((rsg + 128 < nrem) ? rsg + 128 : 0);
  const char* pA0 = (const char*)H + (size_t)ix0 * 1024 + qs;
  const char* pA1 = (const char*)H + (size_t)ix1 * 1024 + qs;
  const int nt0 = (cbase >> 6) + bx * 2;
  const char* pB = (const char*)w2i + ((size_t)(e * 16 + nt0 + (wave >> 2)) * 16) * 4096 + bso;
  G4_BODY(16);
  #pragma unroll
  for (int ni = 0; ni < 4; ++ni) {
    int ycol = bx * 128 + wn * 64 + ni * 16 + f;
    float bb = b2[e * 1024 + cbase + ycol];
    #pragma unroll
    for (int mi = 0; mi < 4; ++mi) {
      int row = wm * 64 + mi * 16 + g * 4;
      #pragma unroll
      for (int r = 0; r < 4; ++r) {
        if (row + r < nrem)
          Y[(size_t)(off_e + m0 + row + r) * 512 + ycol] = f2bf(acc[mi][ni][r] + bb);
      }
    }
  }
}

// ---------------------------------------------------------------- kernels ----
__global__ __launch_bounds__(256) void prep_kernel(
    const float* x, const float* gw, const float* gb, int* idx, float* wts,
    unsigned short* xb,
    const float* w1, const float* w3, unsigned short* w13i,
    const float* w2, unsigned short* w2i,
    const float* sw1, const float* sw3, unsigned short* s13i,
    const float* sw2, unsigned short* sw2i) {
  int b = blockIdx.x;
  if (b < 8192) { gate_body(b, x, gw, gb, idx, wts, xb); return; }
  b -= 8192;
  if (b < 4096) { repack13_body(b, w1, w3, w13i, 1024, 512, 16); return; }
  b -= 4096;
  if (b < 2048) { repack_body(b, w2, w2i, 512, 1024, 256); return; }
  b -= 2048;
  if (b < 256) { repack13_body(b, sw1, sw3, s13i, 1024, 1024, 32); return; }
  b -= 256;
  repack_body(b, sw2, sw2i, 1024, 1024, 512);
}

__global__ __launch_bounds__(256) void count_kernel(const int* __restrict__ idx,
                                                    int* __restrict__ meta) {
  __shared__ int h[32];
  int tid = threadIdx.x;
  if (tid < 32) h[tid] = 0;
  __syncthreads();
  atomicAdd(&h[idx[blockIdx.x * 256 + tid]], 1);
  __syncthreads();
  if (tid < 32 && h[tid]) atomicAdd(&meta[tid], h[tid]);
}

__global__ void scan_kernel(int* __restrict__ meta) {
  int lane = threadIdx.x & 63;
  if (lane < 32) {
    int c = meta[lane];
    int pre = c;
    #pragma unroll
    for (int d = 1; d < 32; d <<= 1) { int t = __shfl_up(pre, d); if (lane >= d) pre += t; }
    int excl = pre - c;
    meta[64 + lane] = excl;
    meta[32 + lane] = excl;
    int nt = (c + 255) >> 8;
    int ntp = nt;
    #pragma unroll
    for (int d = 1; d < 32; d <<= 1) { int t = __shfl_up(ntp, d); if (lane >= d) ntp += t; }
    int ntExcl = ntp - nt;
    for (int k = 0; k < nt; ++k) { meta[128 + ntExcl + k] = lane; meta[1184 + ntExcl + k] = k << 8; }
    if (lane == 31) { meta[96] = excl + c; meta[97] = ntExcl + nt; }
  }
}

__global__ __launch_bounds__(256) void scatter_kernel(
    const int* __restrict__ idx, int* __restrict__ meta,
    int* __restrict__ tok, int* __restrict__ inv) {
  int i = blockIdx.x * 256 + threadIdx.x;
  int lane = threadIdx.x & 63;
  int e = idx[i];
  unsigned long long m = ~0ull;
  #pragma unroll
  for (int b = 0; b < 5; ++b) {
    unsigned long long vote = __ballot((e >> b) & 1);
    m &= ((e >> b) & 1) ? vote : ~vote;
  }
  int leader = __ffsll((long long)m) - 1;
  int rank = __popcll(m & ((1ull << lane) - 1));
  int base = 0;
  if (lane == leader) base = atomicAdd(&meta[32 + e], (int)__popcll(m));
  base = __shfl(base, leader);
  int p = base + rank;
  tok[p] = i >> 2;
  inv[i] = p;
}

// standalone GEMM kernels (small path + g2 half1)
__global__ __launch_bounds__(512, 4) void s1_kernel(
    const unsigned short* xb, const unsigned short* w13,
    const float* sb1, const float* sb3, unsigned short* Hs) {
  __shared__ char lds[73728];
  int2 s = xcd_swz(blockIdx.x, 2048, 16);
  s1_body(s.x, s.y, xb, w13, sb1, sb3, Hs, lds);
}
__global__ __launch_bounds__(512, 4) void s2_kernel(
    const unsigned short* Hs, const unsigned short* b2i,
    const float* sb2, float* out) {
  __shared__ char lds[73728];
  int2 s = xcd_swz(blockIdx.x, 1024, 8);
  s2_body(s.x, s.y, Hs, b2i, sb2, out, lds);
}
__global__ __launch_bounds__(512, 4) void g1_kernel(
    const unsigned short* xb, const unsigned short* w13,
    const float* b1, const float* b3, const int* tok, const int* meta,
    unsigned short* H) {
  __shared__ char lds[73728];
  int2 s = xcd_swz(blockIdx.x, 4352, 8);
  g1_body(s.x, s.y, xb, w13, b1, b3, tok, meta, H, lds);
}
__global__ __launch_bounds__(512, 4) void g2_kernel(
    const unsigned short* H, const unsigned short* w2i,
    const float* b2, const int* meta, unsigned short* Y, int cbase) {
  __shared__ char lds[73728];
  int2 s = xcd_swz(blockIdx.x, 2176, 4);
  g2_body(s.x, s.y, H, w2i, b2, meta, Y, cbase, lds);
}

// fused s1 + g1 (big-ws path): 6400 blocks, interleaved 1:2 so both types
// are co-resident on every CU.
__global__ __launch_bounds__(512, 4) void s1g1_kernel(
    const unsigned short* xb, const unsigned short* s13,
    const float* sb1, const float* sb3, unsigned short* Hs,
    const unsigned short* w13, const float* b1, const float* b3,
    const int* tok, const int* meta, unsigned short* H) {
  __shared__ char lds[73728];
  int id = blockIdx.x;
  int type, sub;
  if (id < 6144) {
    if (id % 3 == 0) { type = 0; sub = id / 3; }
    else { type = 1; sub = id - id / 3 - 1; }
  } else { type = 1; sub = 4096 + (id - 6144); }
  if (type == 0) {
    int2 s = xcd_swz(sub, 2048, 16);
    s1_body(s.x, s.y, xb, s13, sb1, sb3, Hs, lds);
  } else {
    int2 s = xcd_swz(sub, 4352, 8);
    g1_body(s.x, s.y, xb, w13, b1, b3, tok, meta, H, lds);
  }
}

// fused s2 + g2(half0): 3200 blocks.
__global__ __launch_bounds__(512, 4) void s2g2_kernel(
    const unsigned short* Hs, const unsigned short* sw2i, const float* sb2,
    float* out, const unsigned short* H, const unsigned short* w2i,
    const float* b2, const int* meta, unsigned short* Y) {
  __shared__ char lds[73728];
  int id = blockIdx.x;
  int type, sub;
  if (id < 3072) {
    if (id % 3 == 0) { type = 0; sub = id / 3; }
    else { type = 1; sub = id - id / 3 - 1; }
  } else { type = 1; sub = 2048 + (id - 3072); }
  if (type == 0) {
    int2 s = xcd_swz(sub, 1024, 8);
    s2_body(s.x, s.y, Hs, sw2i, sb2, out, lds);
  } else {
    int2 s = xcd_swz(sub, 2176, 4);
    g2_body(s.x, s.y, H, w2i, b2, meta, Y, 0, lds);
  }
}

// ------------------------------------------------------------- combine ----
__global__ __launch_bounds__(256) void combine_kernel(
    const unsigned short* __restrict__ Y, const int* __restrict__ inv,
    const float* __restrict__ wts, float* __restrict__ out, int cbase) {
  int t = blockIdx.x * 2 + (threadIdx.x >> 7);
  int c = (threadIdx.x & 127) * 4;
  int4 iv = *(const int4*)(inv + t * 4);
  float4 wv = *(const float4*)(wts + t * 4);
  float* op = out + (size_t)t * 1024 + cbase + c;
  float4 o = *(float4*)op;
  uint2 u;
  u = *(const uint2*)(Y + (size_t)iv.x * 512 + c);
  o.x += wv.x * bflo(u.x); o.y += wv.x * bfhi(u.x);
  o.z += wv.x * bflo(u.y); o.w += wv.x * bfhi(u.y);
  u = *(const uint2*)(Y + (size_t)iv.y * 512 + c);
  o.x += wv.y * bflo(u.x); o.y += wv.y * bfhi(u.x);
  o.z += wv.y * bflo(u.y); o.w += wv.y * bfhi(u.y);
  u = *(const uint2*)(Y + (size_t)iv.z * 512 + c);
  o.x += wv.z * bflo(u.x); o.y += wv.z * bfhi(u.x);
  o.z += wv.z * bflo(u.y); o.w += wv.z * bfhi(u.y);
  u = *(const uint2*)(Y + (size_t)iv.w * 512 + c);
  o.x += wv.w * bflo(u.x); o.y += wv.w * bfhi(u.x);
  o.z += wv.w * bflo(u.y); o.w += wv.w * bfhi(u.y);
  *(float4*)op = o;
}

// ------------------------------------------------------------------ host ----
extern "C" void kernel_launch(void* const* d_in, const int* in_sizes, int n_in,
                              void* d_out, int out_size, void* d_ws, size_t ws_size,
                              hipStream_t stream) {
  const float* x   = (const float*)d_in[0];
  const float* gw  = (const float*)d_in[1];
  const float* gb  = (const float*)d_in[2];
  const float* w1  = (const float*)d_in[3];
  const float* b1  = (const float*)d_in[4];
  const float* w3  = (const float*)d_in[5];
  const float* b3  = (const float*)d_in[6];
  const float* w2  = (const float*)d_in[7];
  const float* b2  = (const float*)d_in[8];
  const float* sw1 = (const float*)d_in[9];
  const float* sb1 = (const float*)d_in[10];
  const float* sw3 = (const float*)d_in[11];
  const float* sb3 = (const float*)d_in[12];
  const float* sw2 = (const float*)d_in[13];
  const float* sb2 = (const float*)d_in[14];
  float* out = (float*)d_out;
  char* ws = (char*)d_ws;

  const size_t OFF_XB   = 134217728;
  const size_t OFF_W13I = 201326592;
  const size_t OFF_W2I  = 268435456;
  const size_t OFF_S13I = 301989888;
  const size_t OFF_SW2I = 306184192;
  const size_t OFF_IDX  = 308281344;
  const size_t OFF_WTS  = 308805632;
  const size_t OFF_TOK  = 309329920;
  const size_t OFF_INV  = 309854208;
  const size_t OFF_META = 310378496;
  const size_t OFF_HS   = 310394880;                 // big path only
  const size_t NEED_SMALL = OFF_META + 8960;
  const size_t NEED_BIG   = OFF_HS + 67108864;
  if (ws_size < NEED_SMALL) return;
  const bool big = ws_size >= NEED_BIG;

  unsigned short* H    = (unsigned short*)ws;
  unsigned short* xb   = (unsigned short*)(ws + OFF_XB);
  unsigned short* Yb   = (unsigned short*)(ws + OFF_XB);   // aliases xb+w13i
  unsigned short* w13i = (unsigned short*)(ws + OFF_W13I);
  unsigned short* w2i  = (unsigned short*)(ws + OFF_W2I);
  unsigned short* s13i = (unsigned short*)(ws + OFF_S13I);
  unsigned short* sw2i = (unsigned short*)(ws + OFF_SW2I);
  int*   idx  = (int*)(ws + OFF_IDX);
  float* wts  = (float*)(ws + OFF_WTS);
  int*   tokl = (int*)(ws + OFF_TOK);
  int*   inv  = (int*)(ws + OFF_INV);
  int*   meta = (int*)(ws + OFF_META);
  unsigned short* HsBig = (unsigned short*)(ws + OFF_HS);

  hipMemsetAsync(meta, 0, 128, stream);
  prep_kernel<<<dim3(14720), dim3(256), 0, stream>>>(
      x, gw, gb, idx, wts, xb, w1, w3, w13i, w2, w2i, sw1, sw3, s13i, sw2, sw2i);
  count_kernel<<<dim3(512), dim3(256), 0, stream>>>(idx, meta);
  scan_kernel<<<dim3(1), dim3(64), 0, stream>>>(meta);
  scatter_kernel<<<dim3(512), dim3(256), 0, stream>>>(idx, meta, tokl, inv);

  if (big) {
    s1g1_kernel<<<dim3(6400), dim3(512), 0, stream>>>(
        xb, s13i, sb1, sb3, HsBig, w13i, b1, b3, tokl, meta, H);
    s2g2_kernel<<<dim3(3200), dim3(512), 0, stream>>>(
        HsBig, sw2i, sb2, out, H, w2i, b2, meta, Yb);
    combine_kernel<<<dim3(16384), dim3(256), 0, stream>>>(Yb, inv, wts, out, 0);
    g2_kernel<<<dim3(2176), dim3(512), 0, stream>>>(H, w2i, b2, meta, Yb, 512);
    combine_kernel<<<dim3(16384), dim3(256), 0, stream>>>(Yb, inv, wts, out, 512);
  } else {
    s1_kernel<<<dim3(2048), dim3(512), 0, stream>>>(xb, s13i, sb1, sb3, H);
    s2_kernel<<<dim3(1024), dim3(512), 0, stream>>>(H, sw2i, sb2, out);
    g1_kernel<<<dim3(4352), dim3(512), 0, stream>>>(xb, w13i, b1, b3, tokl, meta, H);
    g2_kernel<<<dim3(2176), dim3(512), 0, stream>>>(H, w2i, b2, meta, Yb, 0);
    combine_kernel<<<dim3(16384), dim3(256), 0, stream>>>(Yb, inv, wts, out, 0);
    g2_kernel<<<dim3(2176), dim3(512), 0, stream>>>(H, w2i, b2, meta, Yb, 512);
    combine_kernel<<<dim3(16384), dim3(256), 0, stream>>>(Yb, inv, wts, out, 512);
  }
}